// Round 7
// baseline (133.366 us; speedup 1.0000x reference)
//
#include <hip/hip_runtime.h>
#include <stdint.h>

#define B_DIM 32768
#define IN_DIM 512
#define OUT_DIM 512

typedef float f32x4 __attribute__((ext_vector_type(4)));

// xi = trunc(v*2^sf); keep top-4 significant bits of |xi|; sign restored.
// fp32-bit path: truncf, then mask mantissa to 3 stored bits (+implicit = 4
// significant). The masked value is an integer with <=4 significant bits and
// |v| <= ~370 < 448 = e4m3 max, so OCP e4m3 represents it EXACTLY ->
// cvt_pk_fp8_f32 is lossless here (verified absmax=0 in R4/R6).
__device__ __forceinline__ float trunc4(float x, float s) {
    uint32_t u = __float_as_uint(truncf(x * s));
    return __uint_as_float(u & 0xFFF00000u);   // sign+exp+3 mantissa bits
}

// Merged quant: one dispatch covers x (nx4 words) then w (nw4 words).
// Read-BW-bound (85 MB ~ 13.5 us at 6.3 TB/s) -> at its roofline.
__global__ void quant_fp8_2(const float* __restrict__ x, const float* __restrict__ w,
                            uint32_t* __restrict__ ox, uint32_t* __restrict__ ow,
                            int nx4, int nw4,
                            const int* __restrict__ asf, const int* __restrict__ wsf) {
    int i = blockIdx.x * blockDim.x + threadIdx.x;
    const float4* in;
    uint32_t* out;
    float scale;
    if (i < nx4) {
        in = (const float4*)x + i;  out = ox + i;  scale = (float)(1 << *asf);
    } else {
        int j = i - nx4;
        if (j >= nw4) return;
        in = (const float4*)w + j;  out = ow + j;  scale = (float)(1 << *wsf);
    }
    float4 v = *in;
    int p = 0;
    p = __builtin_amdgcn_cvt_pk_fp8_f32(trunc4(v.x, scale), trunc4(v.y, scale), p, false);
    p = __builtin_amdgcn_cvt_pk_fp8_f32(trunc4(v.z, scale), trunc4(v.w, scale), p, true);
    *out = (uint32_t)p;   // byte j = element j (k-ascending)
}

// fp8 GEMM, 3-buffer depth-2 counted-vmcnt pipeline (T4 grafted onto the
// verified R6 2-phase structure):
//   iter k: issue glds STAGE(k+2) -> buf[(k+2)%3]
//           ds_read frags + 32 MFMA on buf[k%3]
//           s_waitcnt vmcnt(4) lgkmcnt(0); s_barrier
// vmcnt(4): stage(k+1)'s 4 glds (oldest outstanding, FIFO) have landed;
// stage(k+2)'s 4 stay IN FLIGHT across the barrier — the m218 lever that
// separates 2-phase (655 TF) from deeper pipelines. Never drain to 0 in the
// main loop (only at k=6, when no stage(8) exists).
// WAR-safe: stage(k+2) writes buf[(k-1)%3]; every wave's ds_reads of that
// buffer completed before iter k-1's lgkmcnt(0)+barrier, which precedes these
// glds. Buffer indices are compile-time (full unroll).
// Everything else (tile 128x128, BK=64, 4 waves 2x2, 4x4 MFMA 16x16x32_fp8_fp8,
// LDS swizzle unit p = u ^ (row&6) on the glds global source, ds_read_b64
// frags, epilogue) is byte-identical to the verified R6 kernel.
__global__ __launch_bounds__(256, 3)
void gemm_f8(const uint8_t* __restrict__ A, const uint8_t* __restrict__ W,
             const float* __restrict__ bias, float* __restrict__ C,
             const int* __restrict__ wsf, const int* __restrict__ asf) {
    __shared__ uint8_t As[3][128 * 64];
    __shared__ uint8_t Bs[3][128 * 64];

    const int t    = threadIdx.x;
    const int w    = t >> 6;
    const int lane = t & 63;

    // XCD swizzle: 4 N-blocks of one M-band adjacent on one XCD (A L2 reuse).
    const int b    = blockIdx.x;
    const int xcd  = b & 7;
    const int slot = b >> 3;
    const int bm   = xcd * 32 + (slot >> 2);
    const int bn   = slot & 3;
    const int row0 = bm * 128;
    const int col0 = bn * 128;
    const int wm   = (w & 1) * 64;
    const int wn   = (w >> 1) * 64;

    // staging: pass i covers physical bytes [i*4096 + t*16, +16).
    // row m = i*64 + (t>>2); physical 16B unit j = t&3; global byte offset in
    // row = ((2j) ^ (m&6)) * 8  (16 contiguous bytes = 2 adjacent logical units).
    const int m_st = t >> 2;                       // 0..63 (+i*64; i*64 === 0 mod 8)
    const int goff = ((2 * (t & 3)) ^ (m_st & 6)) * 8;
    const size_t offA = (size_t)(row0 + m_st) * IN_DIM + goff;
    const size_t offB = (size_t)(col0 + m_st) * IN_DIM + goff;

    f32x4 acc[4][4];
    #pragma unroll
    for (int mt = 0; mt < 4; ++mt)
        #pragma unroll
        for (int nt = 0; nt < 4; ++nt)
            acc[mt][nt] = 0.0f;

    // ---- prologue: stage tiles 0 and 1; wait only for tile 0 (vmcnt(4)) ----
    #pragma unroll
    for (int s = 0; s < 2; ++s) {
        #pragma unroll
        for (int i = 0; i < 2; ++i) {
            const uint8_t* ga = A + offA + (size_t)i * 64 * IN_DIM + s * 64;
            uint8_t*       la = &As[s][i * 4096 + w * 1024];   // + lane*16B by HW
            __builtin_amdgcn_global_load_lds((const __attribute__((address_space(1))) void*)ga,
                                             (__attribute__((address_space(3))) void*)la, 16, 0, 0);
            const uint8_t* gb = W + offB + (size_t)i * 64 * IN_DIM + s * 64;
            uint8_t*       lb = &Bs[s][i * 4096 + w * 1024];
            __builtin_amdgcn_global_load_lds((const __attribute__((address_space(1))) void*)gb,
                                             (__attribute__((address_space(3))) void*)lb, 16, 0, 0);
        }
    }
    asm volatile("s_waitcnt vmcnt(4) lgkmcnt(0)" ::: "memory");
    __builtin_amdgcn_sched_barrier(0);
    __builtin_amdgcn_s_barrier();
    __builtin_amdgcn_sched_barrier(0);

    #pragma unroll
    for (int k = 0; k < 8; ++k) {
        const int cur = k % 3;
        const int pre = (k + 2) % 3;

        // ---- issue STAGE(k+2) -> buf[pre]: in flight across this phase AND
        // the next barrier (counted vmcnt keeps it outstanding) ----
        if (k < 6) {
            #pragma unroll
            for (int i = 0; i < 2; ++i) {
                const uint8_t* ga = A + offA + (size_t)i * 64 * IN_DIM + (k + 2) * 64;
                uint8_t*       la = &As[pre][i * 4096 + w * 1024];
                __builtin_amdgcn_global_load_lds((const __attribute__((address_space(1))) void*)ga,
                                                 (__attribute__((address_space(3))) void*)la, 16, 0, 0);
                const uint8_t* gb = W + offB + (size_t)i * 64 * IN_DIM + (k + 2) * 64;
                uint8_t*       lb = &Bs[pre][i * 4096 + w * 1024];
                __builtin_amdgcn_global_load_lds((const __attribute__((address_space(1))) void*)gb,
                                                 (__attribute__((address_space(3))) void*)lb, 16, 0, 0);
            }
        }
        __builtin_amdgcn_sched_barrier(0);   // pin: glds issued before compute

        // ---- MFMA phase on buffers[cur] ----
        {
            const int q  = lane >> 4;
            const int rl = lane & 15;
            const int sx = rl & 6;              // = row&6 (wm, mt*16 are mult of 8)
            #pragma unroll
            for (int ks = 0; ks < 2; ++ks) {
                const int c  = ks * 4 + q;      // logical 8B k-unit
                const int cb = (c ^ sx) * 8;    // swizzled byte offset in row
                long af[4], bfr[4];
                #pragma unroll
                for (int mt = 0; mt < 4; ++mt)
                    af[mt] = *(const long*)(&As[cur][0] + (wm + mt * 16 + rl) * 64 + cb);
                #pragma unroll
                for (int nt = 0; nt < 4; ++nt)
                    bfr[nt] = *(const long*)(&Bs[cur][0] + (wn + nt * 16 + rl) * 64 + cb);
                #pragma unroll
                for (int mt = 0; mt < 4; ++mt)
                    #pragma unroll
                    for (int nt = 0; nt < 4; ++nt)
                        acc[mt][nt] = __builtin_amdgcn_mfma_f32_16x16x32_fp8_fp8(af[mt], bfr[nt], acc[mt][nt], 0, 0, 0);
            }
        }

        // ---- counted wait + barrier (ONE per K-step, never drain mid-loop) --
        // vmcnt(4): stage(k+1) landed, stage(k+2) still outstanding.
        // lgkmcnt(0): my ds_reads of buf[cur] done before anyone overwrites it.
        if (k < 7) {
            if (k < 6) {
                asm volatile("s_waitcnt vmcnt(4) lgkmcnt(0)" ::: "memory");
            } else {
                asm volatile("s_waitcnt vmcnt(0) lgkmcnt(0)" ::: "memory");
            }
            __builtin_amdgcn_sched_barrier(0);
            __builtin_amdgcn_s_barrier();
            __builtin_amdgcn_sched_barrier(0);
        }
    }

    // epilogue: C/D layout col=lane&15, row=(lane>>4)*4+reg (dtype-independent)
    const float oscale = ldexpf(1.0f, -(*wsf + *asf));
    const int cl = lane & 15;
    const int rg = (lane >> 4) * 4;
    #pragma unroll
    for (int nt = 0; nt < 4; ++nt) {
        const int col = col0 + wn + nt * 16 + cl;
        const float bv = bias[col];
        #pragma unroll
        for (int mt = 0; mt < 4; ++mt) {
            f32x4 a = acc[mt][nt];
            #pragma unroll
            for (int r = 0; r < 4; ++r) {
                const int row = row0 + wm + mt * 16 + rg + r;
                C[(size_t)row * OUT_DIM + col] = a[r] * oscale + bv;
            }
        }
    }
}

extern "C" void kernel_launch(void* const* d_in, const int* in_sizes, int n_in,
                              void* d_out, int out_size, void* d_ws, size_t ws_size,
                              hipStream_t stream) {
    const float* x    = (const float*)d_in[0];
    const float* wgt  = (const float*)d_in[1];
    const float* bias = (const float*)d_in[2];
    const int*   wsf  = (const int*)d_in[3];
    const int*   asf  = (const int*)d_in[4];

    uint8_t* tx = (uint8_t*)d_ws;
    uint8_t* tw = (uint8_t*)d_ws + (size_t)B_DIM * IN_DIM;

    const int nx4 = B_DIM * IN_DIM / 4;
    const int nw4 = OUT_DIM * IN_DIM / 4;
    quant_fp8_2<<<(nx4 + nw4 + 255) / 256, 256, 0, stream>>>(
        x, wgt, (uint32_t*)tx, (uint32_t*)tw, nx4, nw4, asf, wsf);

    const int grid = (B_DIM / 128) * (OUT_DIM / 128); // 1024
    gemm_f8<<<grid, 256, 0, stream>>>(tx, tw, bias, (float*)d_out, wsf, asf);
}